// Round 4
// baseline (290.185 us; speedup 1.0000x reference)
//
#include <hip/hip_runtime.h>
#include <hip/hip_bf16.h>
#include <cstdint>

// GCN layer: y = relu(dnorm_n * (adj @ (dnorm_m * x @ W)) + b)
// B=128, N=512, F_IN=F_OUT=128, fp32 in/out. bf16 MFMA internally.
// Pipeline: k_prep (W^T bf16) ; k_degc (dnorm + adj->bf16) ; k_xw (h1t = dnorm_m*xW, bf16, transposed)
//           ; k_agg (adj_bf16 @ h1t, dnorm_n+bias+relu epilogue)

#define BATCH 128
#define NN    512
#define FIN   128
#define FOUT  128

typedef unsigned short u16;
typedef __attribute__((ext_vector_type(8))) __bf16 bfrag;   // 8 bf16 = 4 VGPRs
typedef __attribute__((ext_vector_type(4))) float  f32x4;

__device__ __forceinline__ u16 f2bf(float f) {
    uint32_t u = __builtin_bit_cast(uint32_t, f);
    u += 0x7fffu + ((u >> 16) & 1u);          // round-nearest-even
    return (u16)(u >> 16);
}
__device__ __forceinline__ ushort4 f2bf4(float4 v) {
    ushort4 r;
    r.x = f2bf(v.x); r.y = f2bf(v.y); r.z = f2bf(v.z); r.w = f2bf(v.w);
    return r;
}

// ---------------- k_prep: Wt[g][k] = bf16(W[k][g]) --------------------------
__global__ __launch_bounds__(256) void k_prep(const float* __restrict__ W,
                                              u16* __restrict__ Wt) {
    int idx = blockIdx.x * 256 + threadIdx.x;   // grid 64 -> 16384 elements
    int g = idx >> 7, k = idx & 127;
    Wt[idx] = f2bf(W[k * FOUT + g]);
}

// ---------- k_degc: dnorm[row] = rsqrt(rowsum(adj)); adjb = bf16(adj) -------
// one wave per row; lane handles 8 contiguous floats (32 B load, 16 B store)
__global__ __launch_bounds__(256) void k_degc(const float* __restrict__ adj,
                                              float* __restrict__ dnorm,
                                              u16* __restrict__ adjb) {
    int wave = threadIdx.x >> 6;
    int lane = threadIdx.x & 63;
    size_t row = (size_t)(blockIdx.x << 2) + wave;      // [0, B*N)
    const float4* p = (const float4*)(adj + row * NN);
    float4 v0 = p[2 * lane];
    float4 v1 = p[2 * lane + 1];
    ushort4 b0 = f2bf4(v0), b1 = f2bf4(v1);
    uint4 pack;
    pack.x = (uint32_t)b0.x | ((uint32_t)b0.y << 16);
    pack.y = (uint32_t)b0.z | ((uint32_t)b0.w << 16);
    pack.z = (uint32_t)b1.x | ((uint32_t)b1.y << 16);
    pack.w = (uint32_t)b1.z | ((uint32_t)b1.w << 16);
    *(uint4*)(adjb + row * NN + lane * 8) = pack;
    float s = v0.x + v0.y + v0.z + v0.w + v1.x + v1.y + v1.z + v1.w;
    #pragma unroll
    for (int off = 32; off > 0; off >>= 1) s += __shfl_down(s, off, 64);
    if (lane == 0) dnorm[row] = (s > 0.f) ? rsqrtf(s) : 0.f;
}

// ---------------- k_xw: h1t[b][g][m] = bf16(dnorm[bm] * (x @ W)[bm][g]) -----
// 128-row tile x 128 cols; 4 waves, each 4x4 grid of 16x16x32 bf16 MFMA
__global__ __launch_bounds__(256) void k_xw(const float* __restrict__ x,
                                            const u16* __restrict__ Wt,
                                            const float* __restrict__ dnorm,
                                            u16* __restrict__ h1t) {
    __shared__ u16 As[128][40];   // As[m][k] bf16, row pad to 40 (80 B)
    __shared__ u16 Bs[128][40];   // Bs[g][k] bf16 (Wt is already [g][k])
    __shared__ float sDn[128];

    int tid  = threadIdx.x;
    int row0 = blockIdx.x * 128;                 // global node-row base
    int wave = tid >> 6, lane = tid & 63;
    int wr = wave >> 1, wc = wave & 1;
    int q = lane >> 4, l16 = lane & 15;

    if (tid < 128) sDn[tid] = dnorm[row0 + tid];

    f32x4 acc[4][4];
    #pragma unroll
    for (int i = 0; i < 4; i++)
        #pragma unroll
        for (int j = 0; j < 4; j++) acc[i][j] = (f32x4)(0.f);

    for (int kt = 0; kt < FIN; kt += 32) {
        // stage A: x fp32 -> bf16 (128 m-rows x 32 k)
        #pragma unroll
        for (int j = 0; j < 4; j++) {
            int linear = tid + j * 256;          // 0..1023 float4 slots
            int m = linear >> 3, k4 = (linear & 7) << 2;
            float4 v = *(const float4*)(x + (size_t)(row0 + m) * FIN + kt + k4);
            *(ushort4*)&As[m][k4] = f2bf4(v);
        }
        // stage B: Wt bf16, 128 g-rows x 32 k = 512 uint4 slots (4 per row)
        #pragma unroll
        for (int j = 0; j < 2; j++) {
            int linear = tid + j * 256;          // 0..511
            int g = linear >> 2, k8 = (linear & 3) << 3;
            *(uint4*)&Bs[g][k8] = *(const uint4*)(Wt + (size_t)g * FIN + kt + k8);
        }
        __syncthreads();
        bfrag aF[4], bF[4];
        #pragma unroll
        for (int i = 0; i < 4; i++) aF[i] = *(const bfrag*)&As[wr * 64 + i * 16 + l16][q * 8];
        #pragma unroll
        for (int j = 0; j < 4; j++) bF[j] = *(const bfrag*)&Bs[wc * 64 + j * 16 + l16][q * 8];
        #pragma unroll
        for (int i = 0; i < 4; i++)
            #pragma unroll
            for (int j = 0; j < 4; j++)
                acc[i][j] = __builtin_amdgcn_mfma_f32_16x16x32_bf16(aF[i], bF[j], acc[i][j], 0, 0, 0);
        __syncthreads();
    }

    // epilogue: scale rows by dnorm, store transposed bf16
    int bb = row0 >> 9;                  // batch
    int mb = row0 & 511;                 // node base within batch
    #pragma unroll
    for (int i = 0; i < 4; i++) {
        int mloc = wr * 64 + i * 16 + q * 4;
        float d0 = sDn[mloc], d1 = sDn[mloc + 1], d2 = sDn[mloc + 2], d3 = sDn[mloc + 3];
        #pragma unroll
        for (int j = 0; j < 4; j++) {
            int g = wc * 64 + j * 16 + l16;
            f32x4 c = acc[i][j];
            ushort4 v;
            v.x = f2bf(c[0] * d0); v.y = f2bf(c[1] * d1);
            v.z = f2bf(c[2] * d2); v.w = f2bf(c[3] * d3);
            *(ushort4*)(h1t + ((size_t)bb * FOUT + g) * NN + mb + mloc) = v;
        }
    }
}

// ---------------- k_agg: out = relu(dnorm_n * (adjb @ h1) + bias) -----------
// per batch 512x128; block = 128 rows x 128 cols, K=512 in BK=32 steps.
// adjb/h1t are bf16 -> staging is pure uint4 copies with 1-step reg prefetch.
__global__ __launch_bounds__(256) void k_agg(const u16* __restrict__ adjb,
                                             const u16* __restrict__ h1t,
                                             const float* __restrict__ dnorm,
                                             const float* __restrict__ bias,
                                             float* __restrict__ out) {
    __shared__ u16 As[128][40];   // As[n][k], pad 40 (2-way-free LDS banks)
    __shared__ u16 Bs[128][40];   // Bs[g][k]
    __shared__ float sDn[128];
    __shared__ float sBias[128];

    int tid = threadIdx.x;
    int b   = blockIdx.y;
    int n0  = blockIdx.x * 128;
    int wave = tid >> 6, lane = tid & 63;
    int wr = wave >> 1, wc = wave & 1;
    int q = lane >> 4, l16 = lane & 15;

    const u16* A  = adjb + (size_t)b * NN * NN;
    const u16* Bm = h1t + (size_t)b * FOUT * NN;
    if (tid < 128) { sDn[tid] = dnorm[(size_t)b * NN + n0 + tid]; sBias[tid] = bias[tid]; }

    // staging slot mapping: slot = tid + j*256, j in {0,1}; 512 uint4 slots per tile
    int mA[2], cA[2];
    #pragma unroll
    for (int j = 0; j < 2; j++) { int s = tid + j * 256; mA[j] = s >> 2; cA[j] = (s & 3) << 3; }

    f32x4 acc[4][4];
    #pragma unroll
    for (int i = 0; i < 4; i++)
        #pragma unroll
        for (int j = 0; j < 4; j++) acc[i][j] = (f32x4)(0.f);

    uint4 pa[2], pb[2];
    #pragma unroll
    for (int j = 0; j < 2; j++) {
        pa[j] = *(const uint4*)(A  + (size_t)(n0 + mA[j]) * NN + cA[j]);
        pb[j] = *(const uint4*)(Bm + (size_t)mA[j] * NN + cA[j]);
    }

    for (int kt = 0; kt < NN; kt += 32) {
        __syncthreads();               // previous iter's ds_reads complete
        #pragma unroll
        for (int j = 0; j < 2; j++) {
            *(uint4*)&As[mA[j]][cA[j]] = pa[j];
            *(uint4*)&Bs[mA[j]][cA[j]] = pb[j];
        }
        __syncthreads();
        if (kt + 32 < NN) {
            int kn = kt + 32;
            #pragma unroll
            for (int j = 0; j < 2; j++) {
                pa[j] = *(const uint4*)(A  + (size_t)(n0 + mA[j]) * NN + kn + cA[j]);
                pb[j] = *(const uint4*)(Bm + (size_t)mA[j] * NN + kn + cA[j]);
            }
        }
        bfrag aF[4], bF[4];
        #pragma unroll
        for (int i = 0; i < 4; i++) aF[i] = *(const bfrag*)&As[wr * 64 + i * 16 + l16][q * 8];
        #pragma unroll
        for (int j = 0; j < 4; j++) bF[j] = *(const bfrag*)&Bs[wc * 64 + j * 16 + l16][q * 8];
        #pragma unroll
        for (int i = 0; i < 4; i++)
            #pragma unroll
            for (int j = 0; j < 4; j++)
                acc[i][j] = __builtin_amdgcn_mfma_f32_16x16x32_bf16(aF[i], bF[j], acc[i][j], 0, 0, 0);
    }

    // epilogue: dnorm_n scale + bias + relu, fp32 store
    #pragma unroll
    for (int i = 0; i < 4; i++) {
        int rloc = wr * 64 + i * 16 + q * 4;
        float d0 = sDn[rloc], d1 = sDn[rloc + 1], d2 = sDn[rloc + 2], d3 = sDn[rloc + 3];
        #pragma unroll
        for (int j = 0; j < 4; j++) {
            int col = wc * 64 + j * 16 + l16;
            float bsv = sBias[col];
            f32x4 c = acc[i][j];
            float* o = out + ((size_t)b * NN + n0 + rloc) * FOUT + col;
            o[0 * FOUT] = fmaxf(fmaf(c[0], d0, bsv), 0.f);
            o[1 * FOUT] = fmaxf(fmaf(c[1], d1, bsv), 0.f);
            o[2 * FOUT] = fmaxf(fmaf(c[2], d2, bsv), 0.f);
            o[3 * FOUT] = fmaxf(fmaf(c[3], d3, bsv), 0.f);
        }
    }
}

extern "C" void kernel_launch(void* const* d_in, const int* in_sizes, int n_in,
                              void* d_out, int out_size, void* d_ws, size_t ws_size,
                              hipStream_t stream) {
    const float* adj  = (const float*)d_in[0];
    const float* x    = (const float*)d_in[1];
    const float* W    = (const float*)d_in[2];
    const float* bias = (const float*)d_in[3];
    float* out = (float*)d_out;

    char* ws = (char*)d_ws;
    float* dnorm = (float*)ws;                                   // 256 KB
    u16*   Wt    = (u16*)(ws + (1u << 18));                      // 32 KB
    u16*   h1t   = (u16*)(ws + (1u << 18) + (1u << 15));         // 16.8 MB
    u16*   adjb  = (u16*)(ws + (1u << 18) + (1u << 15) + (size_t)BATCH * NN * FOUT * 2);  // 67 MB

    hipLaunchKernelGGL(k_prep, dim3(64), dim3(256), 0, stream, W, Wt);
    hipLaunchKernelGGL(k_degc, dim3(BATCH * NN / 4), dim3(256), 0, stream, adj, dnorm, adjb);
    hipLaunchKernelGGL(k_xw,   dim3(BATCH * NN / 128), dim3(256), 0, stream, x, Wt, dnorm, h1t);
    hipLaunchKernelGGL(k_agg,  dim3(4, BATCH), dim3(256), 0, stream, adjb, h1t, dnorm, bias, out);
}

// Round 5
// 272.236 us; speedup vs baseline: 1.0659x; 1.0659x over previous
//
#include <hip/hip_runtime.h>
#include <hip/hip_bf16.h>
#include <cstdint>

// GCN layer: y = relu(dnorm_n * (adj @ (dnorm_m * x @ W)) + b)
// B=128, N=512, F_IN=F_OUT=128, fp32 in/out. bf16 MFMA internally.
// R5: R3 dataflow (k_agg reads fp32 adj; no adjb round-trip — R4 lesson) +
//     k_agg BK=64 with register prefetch of next K-tile.

#define BATCH 128
#define NN    512
#define FIN   128
#define FOUT  128

typedef unsigned short u16;
typedef __attribute__((ext_vector_type(8))) __bf16 bfrag;   // 8 bf16 = 4 VGPRs
typedef __attribute__((ext_vector_type(4))) float  f32x4;

__device__ __forceinline__ u16 f2bf(float f) {
    uint32_t u = __builtin_bit_cast(uint32_t, f);
    u += 0x7fffu + ((u >> 16) & 1u);          // round-nearest-even
    return (u16)(u >> 16);
}
__device__ __forceinline__ ushort4 f2bf4(float4 v) {
    ushort4 r;
    r.x = f2bf(v.x); r.y = f2bf(v.y); r.z = f2bf(v.z); r.w = f2bf(v.w);
    return r;
}

// ---------------- k_prep: Wt[g][k] = bf16(W[k][g]) --------------------------
__global__ __launch_bounds__(256) void k_prep(const float* __restrict__ W,
                                              u16* __restrict__ Wt) {
    int idx = blockIdx.x * 256 + threadIdx.x;   // grid 64 -> 16384 elements
    int g = idx >> 7, k = idx & 127;
    Wt[idx] = f2bf(W[k * FOUT + g]);
}

// ---------------- k_deg: dnorm[row] = rsqrt(rowsum(adj)) --------------------
__global__ __launch_bounds__(256) void k_deg(const float* __restrict__ adj,
                                             float* __restrict__ dnorm) {
    int wave = threadIdx.x >> 6;
    int lane = threadIdx.x & 63;
    int row  = (blockIdx.x << 2) + wave;          // [0, B*N)
    const float4* p = (const float4*)(adj + (size_t)row * NN);
    float4 v0 = p[lane];
    float4 v1 = p[lane + 64];
    float s = v0.x + v0.y + v0.z + v0.w + v1.x + v1.y + v1.z + v1.w;
    #pragma unroll
    for (int off = 32; off > 0; off >>= 1) s += __shfl_down(s, off, 64);
    if (lane == 0) dnorm[row] = (s > 0.f) ? rsqrtf(s) : 0.f;
}

// ---------------- k_xw: h1t[b][g][m] = bf16(dnorm[bm] * (x @ W)[bm][g]) -----
// 128-row tile x 128 cols; 4 waves, each 4x4 grid of 16x16x32 bf16 MFMA
__global__ __launch_bounds__(256) void k_xw(const float* __restrict__ x,
                                            const u16* __restrict__ Wt,
                                            const float* __restrict__ dnorm,
                                            u16* __restrict__ h1t) {
    __shared__ u16 As[128][40];   // As[m][k] bf16, row pad to 40 (80 B)
    __shared__ u16 Bs[128][40];   // Bs[g][k] bf16 (Wt is already [g][k])
    __shared__ float sDn[128];

    int tid  = threadIdx.x;
    int row0 = blockIdx.x * 128;                 // global node-row base
    int wave = tid >> 6, lane = tid & 63;
    int wr = wave >> 1, wc = wave & 1;
    int q = lane >> 4, l16 = lane & 15;

    if (tid < 128) sDn[tid] = dnorm[row0 + tid];

    f32x4 acc[4][4];
    #pragma unroll
    for (int i = 0; i < 4; i++)
        #pragma unroll
        for (int j = 0; j < 4; j++) acc[i][j] = (f32x4)(0.f);

    for (int kt = 0; kt < FIN; kt += 32) {
        // stage A: x fp32 -> bf16 (128 m-rows x 32 k)
        #pragma unroll
        for (int j = 0; j < 4; j++) {
            int linear = tid + j * 256;          // 0..1023 float4 slots
            int m = linear >> 3, k4 = (linear & 7) << 2;
            float4 v = *(const float4*)(x + (size_t)(row0 + m) * FIN + kt + k4);
            *(ushort4*)&As[m][k4] = f2bf4(v);
        }
        // stage B: Wt bf16, 128 g-rows x 32 k = 512 uint4 slots (4 per row)
        #pragma unroll
        for (int j = 0; j < 2; j++) {
            int linear = tid + j * 256;          // 0..511
            int g = linear >> 2, k8 = (linear & 3) << 3;
            *(uint4*)&Bs[g][k8] = *(const uint4*)(Wt + (size_t)g * FIN + kt + k8);
        }
        __syncthreads();
        bfrag aF[4], bF[4];
        #pragma unroll
        for (int i = 0; i < 4; i++) aF[i] = *(const bfrag*)&As[wr * 64 + i * 16 + l16][q * 8];
        #pragma unroll
        for (int j = 0; j < 4; j++) bF[j] = *(const bfrag*)&Bs[wc * 64 + j * 16 + l16][q * 8];
        #pragma unroll
        for (int i = 0; i < 4; i++)
            #pragma unroll
            for (int j = 0; j < 4; j++)
                acc[i][j] = __builtin_amdgcn_mfma_f32_16x16x32_bf16(aF[i], bF[j], acc[i][j], 0, 0, 0);
        __syncthreads();
    }

    // epilogue: scale rows by dnorm, store transposed bf16
    int bb = row0 >> 9;                  // batch
    int mb = row0 & 511;                 // node base within batch
    #pragma unroll
    for (int i = 0; i < 4; i++) {
        int mloc = wr * 64 + i * 16 + q * 4;
        float d0 = sDn[mloc], d1 = sDn[mloc + 1], d2 = sDn[mloc + 2], d3 = sDn[mloc + 3];
        #pragma unroll
        for (int j = 0; j < 4; j++) {
            int g = wc * 64 + j * 16 + l16;
            f32x4 c = acc[i][j];
            ushort4 v;
            v.x = f2bf(c[0] * d0); v.y = f2bf(c[1] * d1);
            v.z = f2bf(c[2] * d2); v.w = f2bf(c[3] * d3);
            *(ushort4*)(h1t + ((size_t)bb * FOUT + g) * NN + mb + mloc) = v;
        }
    }
}

// ---------------- k_agg: out = relu(dnorm_n * (adj @ h1) + bias) ------------
// per batch 512x128; block = 128 rows x 128 cols, K=512 in BK=64 steps.
// fp32 adj staged with cvt (L3-resident after k_deg); register prefetch of
// next K-tile overlaps global latency with the MFMA phase.
__global__ __launch_bounds__(256) void k_agg(const float* __restrict__ adj,
                                             const u16* __restrict__ h1t,
                                             const float* __restrict__ dnorm,
                                             const float* __restrict__ bias,
                                             float* __restrict__ out) {
    __shared__ u16 As[128][72];   // As[n][k] bf16, BK=64, pad 72 (balanced banks)
    __shared__ u16 Bs[128][72];   // Bs[g][k]
    __shared__ float sDn[128];
    __shared__ float sBias[128];

    int tid = threadIdx.x;
    int b   = blockIdx.y;
    int n0  = blockIdx.x * 128;
    int wave = tid >> 6, lane = tid & 63;
    int wr = wave >> 1, wc = wave & 1;
    int q = lane >> 4, l16 = lane & 15;

    const float* A  = adj + (size_t)b * NN * NN;
    const u16*   Bm = h1t + (size_t)b * FOUT * NN;
    if (tid < 128) { sDn[tid] = dnorm[(size_t)b * NN + n0 + tid]; sBias[tid] = bias[tid]; }

    // staging maps: A = 128 rows x 64 k fp32 -> 2048 float4 slots (8/thread)
    //               B = 128 g    x 64 k bf16 -> 1024 uint4 slots (4/thread)
    int mA[8], kA[8];
    #pragma unroll
    for (int j = 0; j < 8; j++) { int s = tid + j * 256; mA[j] = s >> 4; kA[j] = (s & 15) << 2; }
    int gB[4], kB[4];
    #pragma unroll
    for (int j = 0; j < 4; j++) { int s = tid + j * 256; gB[j] = s >> 3; kB[j] = (s & 7) << 3; }

    f32x4 acc[4][4];
    #pragma unroll
    for (int i = 0; i < 4; i++)
        #pragma unroll
        for (int j = 0; j < 4; j++) acc[i][j] = (f32x4)(0.f);

    float4 pa[8];
    uint4  pb[4];
    #pragma unroll
    for (int j = 0; j < 8; j++) pa[j] = *(const float4*)(A + (size_t)(n0 + mA[j]) * NN + kA[j]);
    #pragma unroll
    for (int j = 0; j < 4; j++) pb[j] = *(const uint4*)(Bm + (size_t)gB[j] * NN + kB[j]);

    for (int kt = 0; kt < NN; kt += 64) {
        __syncthreads();               // previous iter's ds_reads complete
        #pragma unroll
        for (int j = 0; j < 8; j++) *(ushort4*)&As[mA[j]][kA[j]] = f2bf4(pa[j]);
        #pragma unroll
        for (int j = 0; j < 4; j++) *(uint4*)&Bs[gB[j]][kB[j]] = pb[j];
        __syncthreads();
        if (kt + 64 < NN) {
            int kn = kt + 64;
            #pragma unroll
            for (int j = 0; j < 8; j++) pa[j] = *(const float4*)(A + (size_t)(n0 + mA[j]) * NN + kn + kA[j]);
            #pragma unroll
            for (int j = 0; j < 4; j++) pb[j] = *(const uint4*)(Bm + (size_t)gB[j] * NN + kn + kB[j]);
        }
        #pragma unroll
        for (int ks = 0; ks < 64; ks += 32) {
            bfrag aF[4], bF[4];
            #pragma unroll
            for (int i = 0; i < 4; i++) aF[i] = *(const bfrag*)&As[wr * 64 + i * 16 + l16][ks + q * 8];
            #pragma unroll
            for (int j = 0; j < 4; j++) bF[j] = *(const bfrag*)&Bs[wc * 64 + j * 16 + l16][ks + q * 8];
            #pragma unroll
            for (int i = 0; i < 4; i++)
                #pragma unroll
                for (int j = 0; j < 4; j++)
                    acc[i][j] = __builtin_amdgcn_mfma_f32_16x16x32_bf16(aF[i], bF[j], acc[i][j], 0, 0, 0);
        }
    }

    // epilogue: dnorm_n scale + bias + relu, fp32 store
    #pragma unroll
    for (int i = 0; i < 4; i++) {
        int rloc = wr * 64 + i * 16 + q * 4;
        float d0 = sDn[rloc], d1 = sDn[rloc + 1], d2 = sDn[rloc + 2], d3 = sDn[rloc + 3];
        #pragma unroll
        for (int j = 0; j < 4; j++) {
            int col = wc * 64 + j * 16 + l16;
            float bsv = sBias[col];
            f32x4 c = acc[i][j];
            float* o = out + ((size_t)b * NN + n0 + rloc) * FOUT + col;
            o[0 * FOUT] = fmaxf(fmaf(c[0], d0, bsv), 0.f);
            o[1 * FOUT] = fmaxf(fmaf(c[1], d1, bsv), 0.f);
            o[2 * FOUT] = fmaxf(fmaf(c[2], d2, bsv), 0.f);
            o[3 * FOUT] = fmaxf(fmaf(c[3], d3, bsv), 0.f);
        }
    }
}

extern "C" void kernel_launch(void* const* d_in, const int* in_sizes, int n_in,
                              void* d_out, int out_size, void* d_ws, size_t ws_size,
                              hipStream_t stream) {
    const float* adj  = (const float*)d_in[0];
    const float* x    = (const float*)d_in[1];
    const float* W    = (const float*)d_in[2];
    const float* bias = (const float*)d_in[3];
    float* out = (float*)d_out;

    char* ws = (char*)d_ws;
    float* dnorm = (float*)ws;                                   // 256 KB
    u16*   Wt    = (u16*)(ws + (1u << 18));                      // 32 KB
    u16*   h1t   = (u16*)(ws + (1u << 18) + (1u << 15));         // 16.8 MB

    hipLaunchKernelGGL(k_prep, dim3(64), dim3(256), 0, stream, W, Wt);
    hipLaunchKernelGGL(k_deg,  dim3(BATCH * NN / 4), dim3(256), 0, stream, adj, dnorm);
    hipLaunchKernelGGL(k_xw,   dim3(BATCH * NN / 128), dim3(256), 0, stream, x, Wt, dnorm, h1t);
    hipLaunchKernelGGL(k_agg,  dim3(4, BATCH), dim3(256), 0, stream, adj, h1t, dnorm, bias, out);
}

// Round 6
// 267.857 us; speedup vs baseline: 1.0834x; 1.0163x over previous
//
#include <hip/hip_runtime.h>
#include <hip/hip_bf16.h>
#include <cstdint>

// GCN layer: y = relu(dnorm_n * (adj @ (dnorm_m * x @ W)) + b)
// B=128, N=512, F_IN=F_OUT=128, fp32 in/out. bf16 MFMA internally.
// R6: R3 dataflow + k_agg single-barrier LDS double-buffer + k_prep fused into k_deg.

#define BATCH 128
#define NN    512
#define FIN   128
#define FOUT  128

typedef unsigned short u16;
typedef __attribute__((ext_vector_type(8))) __bf16 bfrag;   // 8 bf16 = 4 VGPRs
typedef __attribute__((ext_vector_type(4))) float  f32x4;

__device__ __forceinline__ u16 f2bf(float f) {
    uint32_t u = __builtin_bit_cast(uint32_t, f);
    u += 0x7fffu + ((u >> 16) & 1u);          // round-nearest-even
    return (u16)(u >> 16);
}
__device__ __forceinline__ ushort4 f2bf4(float4 v) {
    ushort4 r;
    r.x = f2bf(v.x); r.y = f2bf(v.y); r.z = f2bf(v.z); r.w = f2bf(v.w);
    return r;
}

// -------- k_deg: dnorm[row] = rsqrt(rowsum(adj));  blocks<64 also do W^T ----
__global__ __launch_bounds__(256) void k_deg(const float* __restrict__ adj,
                                             float* __restrict__ dnorm,
                                             const float* __restrict__ W,
                                             u16* __restrict__ Wt) {
    int wave = threadIdx.x >> 6;
    int lane = threadIdx.x & 63;
    int row  = (blockIdx.x << 2) + wave;          // [0, B*N)
    const float4* p = (const float4*)(adj + (size_t)row * NN);
    float4 v0 = p[lane];
    float4 v1 = p[lane + 64];
    float s = v0.x + v0.y + v0.z + v0.w + v1.x + v1.y + v1.z + v1.w;
    #pragma unroll
    for (int off = 32; off > 0; off >>= 1) s += __shfl_down(s, off, 64);
    if (lane == 0) dnorm[row] = (s > 0.f) ? rsqrtf(s) : 0.f;
    // fused k_prep: Wt[g][k] = bf16(W[k][g]) for first 64 blocks
    if (blockIdx.x < 64) {
        int idx = blockIdx.x * 256 + threadIdx.x;   // 16384 elements
        int g = idx >> 7, k = idx & 127;
        Wt[idx] = f2bf(W[k * FOUT + g]);
    }
}

// ---------------- k_xw: h1t[b][g][m] = bf16(dnorm[bm] * (x @ W)[bm][g]) -----
// 128-row tile x 128 cols; 4 waves, each 4x4 grid of 16x16x32 bf16 MFMA
__global__ __launch_bounds__(256) void k_xw(const float* __restrict__ x,
                                            const u16* __restrict__ Wt,
                                            const float* __restrict__ dnorm,
                                            u16* __restrict__ h1t) {
    __shared__ u16 As[128][40];   // As[m][k] bf16, row pad to 40 (80 B)
    __shared__ u16 Bs[128][40];   // Bs[g][k] bf16 (Wt is already [g][k])
    __shared__ float sDn[128];

    int tid  = threadIdx.x;
    int row0 = blockIdx.x * 128;                 // global node-row base
    int wave = tid >> 6, lane = tid & 63;
    int wr = wave >> 1, wc = wave & 1;
    int q = lane >> 4, l16 = lane & 15;

    if (tid < 128) sDn[tid] = dnorm[row0 + tid];

    f32x4 acc[4][4];
    #pragma unroll
    for (int i = 0; i < 4; i++)
        #pragma unroll
        for (int j = 0; j < 4; j++) acc[i][j] = (f32x4)(0.f);

    for (int kt = 0; kt < FIN; kt += 32) {
        // stage A: x fp32 -> bf16 (128 m-rows x 32 k)
        #pragma unroll
        for (int j = 0; j < 4; j++) {
            int linear = tid + j * 256;          // 0..1023 float4 slots
            int m = linear >> 3, k4 = (linear & 7) << 2;
            float4 v = *(const float4*)(x + (size_t)(row0 + m) * FIN + kt + k4);
            *(ushort4*)&As[m][k4] = f2bf4(v);
        }
        // stage B: Wt bf16, 128 g-rows x 32 k = 512 uint4 slots (4 per row)
        #pragma unroll
        for (int j = 0; j < 2; j++) {
            int linear = tid + j * 256;          // 0..511
            int g = linear >> 2, k8 = (linear & 3) << 3;
            *(uint4*)&Bs[g][k8] = *(const uint4*)(Wt + (size_t)g * FIN + kt + k8);
        }
        __syncthreads();
        bfrag aF[4], bF[4];
        #pragma unroll
        for (int i = 0; i < 4; i++) aF[i] = *(const bfrag*)&As[wr * 64 + i * 16 + l16][q * 8];
        #pragma unroll
        for (int j = 0; j < 4; j++) bF[j] = *(const bfrag*)&Bs[wc * 64 + j * 16 + l16][q * 8];
        #pragma unroll
        for (int i = 0; i < 4; i++)
            #pragma unroll
            for (int j = 0; j < 4; j++)
                acc[i][j] = __builtin_amdgcn_mfma_f32_16x16x32_bf16(aF[i], bF[j], acc[i][j], 0, 0, 0);
        __syncthreads();
    }

    // epilogue: scale rows by dnorm, store transposed bf16
    int bb = row0 >> 9;                  // batch
    int mb = row0 & 511;                 // node base within batch
    #pragma unroll
    for (int i = 0; i < 4; i++) {
        int mloc = wr * 64 + i * 16 + q * 4;
        float d0 = sDn[mloc], d1 = sDn[mloc + 1], d2 = sDn[mloc + 2], d3 = sDn[mloc + 3];
        #pragma unroll
        for (int j = 0; j < 4; j++) {
            int g = wc * 64 + j * 16 + l16;
            f32x4 c = acc[i][j];
            ushort4 v;
            v.x = f2bf(c[0] * d0); v.y = f2bf(c[1] * d1);
            v.z = f2bf(c[2] * d2); v.w = f2bf(c[3] * d3);
            *(ushort4*)(h1t + ((size_t)bb * FOUT + g) * NN + mb + mloc) = v;
        }
    }
}

// ---------------- k_agg: out = relu(dnorm_n * (adj @ h1) + bias) ------------
// per batch 512x128; block = 128 rows x 128 cols, K=512 in BK=32 steps.
// Single-barrier ping-pong double buffer: per iter, ds_read frags(tile k)
// then issue global loads(tile k+1), MFMA, then ds_write(tile k+1 -> alt buf).
__global__ __launch_bounds__(256) void k_agg(const float* __restrict__ adj,
                                             const u16* __restrict__ h1t,
                                             const float* __restrict__ dnorm,
                                             const float* __restrict__ bias,
                                             float* __restrict__ out) {
    __shared__ u16 As[2][128][40];   // ping-pong A tiles
    __shared__ u16 Bs[2][128][40];   // ping-pong B tiles
    __shared__ float sDn[128];
    __shared__ float sBias[128];

    int tid = threadIdx.x;
    int b   = blockIdx.y;
    int n0  = blockIdx.x * 128;
    int wave = tid >> 6, lane = tid & 63;
    int wr = wave >> 1, wc = wave & 1;
    int q = lane >> 4, l16 = lane & 15;

    const float* A  = adj + (size_t)b * NN * NN;
    const u16*   Bm = h1t + (size_t)b * FOUT * NN;
    if (tid < 128) { sDn[tid] = dnorm[(size_t)b * NN + n0 + tid]; sBias[tid] = bias[tid]; }

    // staging maps: A = 128 rows x 32 k fp32 -> 1024 float4 slots (4/thread)
    //               B = 128 g    x 32 k bf16 -> 512 uint4 slots (2/thread)
    int mA[4], kA[4];
    #pragma unroll
    for (int j = 0; j < 4; j++) { int s = tid + j * 256; mA[j] = s >> 3; kA[j] = (s & 7) << 2; }
    int gB[2], kB[2];
    #pragma unroll
    for (int j = 0; j < 2; j++) { int s = tid + j * 256; gB[j] = s >> 2; kB[j] = (s & 3) << 3; }

    f32x4 acc[4][4];
    #pragma unroll
    for (int i = 0; i < 4; i++)
        #pragma unroll
        for (int j = 0; j < 4; j++) acc[i][j] = (f32x4)(0.f);

    // prologue: stage tile 0 into buffer 0
    {
        float4 pa[4];
        uint4  pb[2];
        #pragma unroll
        for (int j = 0; j < 4; j++) pa[j] = *(const float4*)(A + (size_t)(n0 + mA[j]) * NN + kA[j]);
        #pragma unroll
        for (int j = 0; j < 2; j++) pb[j] = *(const uint4*)(Bm + (size_t)gB[j] * NN + kB[j]);
        #pragma unroll
        for (int j = 0; j < 4; j++) *(ushort4*)&As[0][mA[j]][kA[j]] = f2bf4(pa[j]);
        #pragma unroll
        for (int j = 0; j < 2; j++) *(uint4*)&Bs[0][gB[j]][kB[j]] = pb[j];
    }

    #pragma unroll 1
    for (int it = 0; it < 16; it++) {
        int buf = it & 1;
        __syncthreads();   // tile `it` staged & visible; alt buffer free to overwrite
        // 1) fragment loads for tile `it`
        bfrag aF[4], bF[4];
        #pragma unroll
        for (int i = 0; i < 4; i++) aF[i] = *(const bfrag*)&As[buf][wr * 64 + i * 16 + l16][q * 8];
        #pragma unroll
        for (int j = 0; j < 4; j++) bF[j] = *(const bfrag*)&Bs[buf][wc * 64 + j * 16 + l16][q * 8];
        // 2) issue global loads for tile it+1 (independent of MFMA below)
        float4 pa[4];
        uint4  pb[2];
        if (it < 15) {
            int kn = (it + 1) * 32;
            #pragma unroll
            for (int j = 0; j < 4; j++) pa[j] = *(const float4*)(A + (size_t)(n0 + mA[j]) * NN + kn + kA[j]);
            #pragma unroll
            for (int j = 0; j < 2; j++) pb[j] = *(const uint4*)(Bm + (size_t)gB[j] * NN + kn + kB[j]);
        }
        // 3) MFMA on tile `it`
        #pragma unroll
        for (int i = 0; i < 4; i++)
            #pragma unroll
            for (int j = 0; j < 4; j++)
                acc[i][j] = __builtin_amdgcn_mfma_f32_16x16x32_bf16(aF[i], bF[j], acc[i][j], 0, 0, 0);
        // 4) stage tile it+1 into alt buffer (reads of that buffer finished
        //    before the barrier at the top of this iteration)
        if (it < 15) {
            #pragma unroll
            for (int j = 0; j < 4; j++) *(ushort4*)&As[buf ^ 1][mA[j]][kA[j]] = f2bf4(pa[j]);
            #pragma unroll
            for (int j = 0; j < 2; j++) *(uint4*)&Bs[buf ^ 1][gB[j]][kB[j]] = pb[j];
        }
    }

    // epilogue: dnorm_n scale + bias + relu, fp32 store
    #pragma unroll
    for (int i = 0; i < 4; i++) {
        int rloc = wr * 64 + i * 16 + q * 4;
        float d0 = sDn[rloc], d1 = sDn[rloc + 1], d2 = sDn[rloc + 2], d3 = sDn[rloc + 3];
        #pragma unroll
        for (int j = 0; j < 4; j++) {
            int col = wc * 64 + j * 16 + l16;
            float bsv = sBias[col];
            f32x4 c = acc[i][j];
            float* o = out + ((size_t)b * NN + n0 + rloc) * FOUT + col;
            o[0 * FOUT] = fmaxf(fmaf(c[0], d0, bsv), 0.f);
            o[1 * FOUT] = fmaxf(fmaf(c[1], d1, bsv), 0.f);
            o[2 * FOUT] = fmaxf(fmaf(c[2], d2, bsv), 0.f);
            o[3 * FOUT] = fmaxf(fmaf(c[3], d3, bsv), 0.f);
        }
    }
}

extern "C" void kernel_launch(void* const* d_in, const int* in_sizes, int n_in,
                              void* d_out, int out_size, void* d_ws, size_t ws_size,
                              hipStream_t stream) {
    const float* adj  = (const float*)d_in[0];
    const float* x    = (const float*)d_in[1];
    const float* W    = (const float*)d_in[2];
    const float* bias = (const float*)d_in[3];
    float* out = (float*)d_out;

    char* ws = (char*)d_ws;
    float* dnorm = (float*)ws;                                   // 256 KB
    u16*   Wt    = (u16*)(ws + (1u << 18));                      // 32 KB
    u16*   h1t   = (u16*)(ws + (1u << 18) + (1u << 15));         // 16.8 MB

    hipLaunchKernelGGL(k_deg, dim3(BATCH * NN / 4), dim3(256), 0, stream, adj, dnorm, W, Wt);
    hipLaunchKernelGGL(k_xw,  dim3(BATCH * NN / 128), dim3(256), 0, stream, x, Wt, dnorm, h1t);
    hipLaunchKernelGGL(k_agg, dim3(4, BATCH), dim3(256), 0, stream, adj, h1t, dnorm, bias, out);
}